// Round 1
// baseline (140.547 us; speedup 1.0000x reference)
//
#include <hip/hip_runtime.h>

#define WSZ 2
#define ZNEAR 0.1f
#define ZFAR 100.0f

// ---------------------------------------------------------------------------
// Kernel 1: fill index z-buffer with -1
// ---------------------------------------------------------------------------
__global__ void init_kernel(int* __restrict__ buf, int total) {
    int tid = blockIdx.x * blockDim.x + threadIdx.x;
    if (tid < total) buf[tid] = -1;
}

// ---------------------------------------------------------------------------
// Kernel 2: per-point projection + bilinear conf sample + index scatter
// idxbuf: [cnt][H2*W2] (local batch chunk), winner = max point index
// ---------------------------------------------------------------------------
__global__ void scatter_kernel(const float* __restrict__ pp,    // [b,7,n]
                               const float* __restrict__ conf,  // [b,n]
                               const float* __restrict__ pose,  // [b,4,4]
                               const float* __restrict__ Kmat,  // [b,3,3]
                               const float* __restrict__ beta,  // [b,1,h,w]
                               const int* __restrict__ d_h,
                               const int* __restrict__ d_w,
                               int* __restrict__ idxbuf,
                               float* __restrict__ out_conf,    // [b,n]
                               int bb0, int cnt, int n) {
    int tid = blockIdx.x * blockDim.x + threadIdx.x;
    int total = cnt * n;
    if (tid >= total) return;
    int local_b = tid / n;
    int i = tid - local_b * n;
    int bb = bb0 + local_b;

    const int h = *d_h, w = *d_w;
    const int H2 = h * WSZ, W2 = w * WSZ;

    const float* P = pose + bb * 16;
    const float* Kb = Kmat + bb * 9;
    const int pbase = (bb * 7) * n + i;
    float px = pp[pbase + 0 * n];
    float py = pp[pbase + 1 * n];
    float pz = pp[pbase + 2 * n];
    float pw = pp[pbase + 3 * n];

    float pc0 = P[0] * px + P[1] * py + P[2]  * pz + P[3]  * pw;
    float pc1 = P[4] * px + P[5] * py + P[6]  * pz + P[7]  * pw;
    float pc2 = P[8] * px + P[9] * py + P[10] * pz + P[11] * pw;

    float fxk = Kb[0], cxk = Kb[2], fyk = Kb[4], cyk = Kb[5];
    float z = fabsf(pc2);
    float xc = pc0 * fxk / z + cxk;
    float yc = pc1 * fyk / z + cyk;

    // ---- conf_sampled: bilinear sample of beta at grid coords (replicate
    //      the reference's fp expression order) ----
    float gx = xc / (float)(w - 1) * 2.0f - 1.0f;
    float gy = -(yc / (float)(h - 1) * 2.0f - 1.0f);
    float ix = (gx + 1.0f) * 0.5f * (float)(w - 1);
    float iy = (gy + 1.0f) * 0.5f * (float)(h - 1);
    float cs = 0.0f;
    if (ix > -1.0f && ix < (float)w && iy > -1.0f && iy < (float)h) {
        float x0f = floorf(ix), y0f = floorf(iy);
        float wx = ix - x0f, wy = iy - y0f;
        int x0 = (int)x0f, y0 = (int)y0f;
        const float* B = beta + (size_t)bb * h * w;
        float t00 = 0.0f, t10 = 0.0f, t01 = 0.0f, t11 = 0.0f;
        if (y0 >= 0 && y0 < h) {
            if (x0 >= 0 && x0 < w)         t00 = B[y0 * w + x0];
            if (x0 + 1 >= 0 && x0 + 1 < w) t10 = B[y0 * w + x0 + 1];
        }
        if (y0 + 1 >= 0 && y0 + 1 < h) {
            if (x0 >= 0 && x0 < w)         t01 = B[(y0 + 1) * w + x0];
            if (x0 + 1 >= 0 && x0 + 1 < w) t11 = B[(y0 + 1) * w + x0 + 1];
        }
        cs = t00 * (1.0f - wx) * (1.0f - wy)
           + t10 * wx * (1.0f - wy)
           + t01 * (1.0f - wx) * wy
           + t11 * wx * wy;
    }
    out_conf[(size_t)bb * n + i] = cs;

    // ---- scatter ----
    float cf = conf[(size_t)bb * n + i];
    float rx = rintf(xc * (float)WSZ);   // jnp.round = half-to-even = rintf
    float ry = rintf(yc * (float)WSZ);
    bool valid = (rx >= 0.0f) && (rx < (float)W2) &&
                 (ry >= 0.0f) && (ry < (float)H2) &&
                 (z >= ZNEAR) && (z <= ZFAR) && (cf > 0.0f);
    if (valid) {
        int xs = (int)rx, ys = (int)ry;
        atomicMax(&idxbuf[local_b * (H2 * W2) + ys * W2 + xs], i);
    }
}

// ---------------------------------------------------------------------------
// Kernel 3: 2x2 max-pool (argmax over winner conf) + vertical flip + outputs
// ---------------------------------------------------------------------------
__global__ void pool_kernel(const float* __restrict__ alpha,  // [b,1,h,w]
                            const float* __restrict__ conf,   // [b,n]
                            const int* __restrict__ idxbuf,   // [cnt][H2*W2]
                            const int* __restrict__ d_h,
                            const int* __restrict__ d_w,
                            float* __restrict__ out_match,    // [b,h,w]
                            float* __restrict__ out_midx,     // [b,h,w] as float
                            int bb0, int cnt, int n) {
    const int h = *d_h, w = *d_w;
    const int hw = h * w;
    int tid = blockIdx.x * blockDim.x + threadIdx.x;
    int total = cnt * hw;
    if (tid >= total) return;
    int local_b = tid / hw;
    int rc = tid - local_b * hw;
    int r = rc / w;
    int c = rc - r * w;
    int bb = bb0 + local_b;

    const int H2 = h * WSZ, W2 = w * WSZ;
    const int hr = h - 1 - r;  // pre-flip window row

    const int* IB = idxbuf + (size_t)local_b * H2 * W2;
    const float* A = alpha + (size_t)bb * hw;
    const float* C = conf + (size_t)bb * n;

    float best = 0.0f;
    int besti = -1;
    #pragma unroll
    for (int a = 0; a < 4; ++a) {
        int dy = a >> 1, dx = a & 1;
        int Y = hr * WSZ + dy, X = c * WSZ + dx;
        int widx = IB[Y * W2 + X];
        if (widx >= 0) {
            // alpha_up (repeat 2x then vflip): alpha[(H2-1-Y)/2][X/2]
            float av = A[((H2 - 1 - Y) >> 1) * w + (X >> 1)];
            if (av > 0.0f) {
                float cv = C[widx];  // scattered conf; always > 0 for winners
                if (cv > best) { best = cv; besti = widx; }  // first-max wins
            }
        }
    }
    int o = bb * hw + rc;
    out_match[o] = (best > 0.0f) ? 1.0f : 0.0f;
    out_midx[o]  = (float)besti;
}

extern "C" void kernel_launch(void* const* d_in, const int* in_sizes, int n_in,
                              void* d_out, int out_size, void* d_ws, size_t ws_size,
                              hipStream_t stream) {
    const float* alpha = (const float*)d_in[0];
    const float* beta  = (const float*)d_in[1];
    const float* pp    = (const float*)d_in[2];
    const float* conf  = (const float*)d_in[3];
    const float* pose  = (const float*)d_in[4];
    const float* Kmat  = (const float*)d_in[5];
    const int*   d_h   = (const int*)d_in[6];
    const int*   d_w   = (const int*)d_in[7];

    const int b  = in_sizes[4] / 16;          // pose is [b,4,4]
    const int n  = in_sizes[3] / b;           // conf is [b,n]
    const int hw = in_sizes[0] / b;           // alpha is [b,1,h,w]

    float* out_match = (float*)d_out;
    float* out_midx  = out_match + (size_t)b * hw;
    float* out_conf  = out_midx + (size_t)b * hw;

    int* idxbuf = (int*)d_ws;
    const size_t per_batch_ints = (size_t)hw * WSZ * WSZ;   // H2*W2
    const size_t per_batch_bytes = per_batch_ints * sizeof(int);
    int chunk = (int)(ws_size / per_batch_bytes);
    if (chunk < 1) chunk = 1;
    if (chunk > b) chunk = b;

    const int BS = 256;
    for (int bb0 = 0; bb0 < b; bb0 += chunk) {
        int cnt = (b - bb0 < chunk) ? (b - bb0) : chunk;

        int init_total = (int)(cnt * per_batch_ints);
        init_kernel<<<(init_total + BS - 1) / BS, BS, 0, stream>>>(idxbuf, init_total);

        int sc_total = cnt * n;
        scatter_kernel<<<(sc_total + BS - 1) / BS, BS, 0, stream>>>(
            pp, conf, pose, Kmat, beta, d_h, d_w, idxbuf, out_conf, bb0, cnt, n);

        int pl_total = cnt * hw;
        pool_kernel<<<(pl_total + BS - 1) / BS, BS, 0, stream>>>(
            alpha, conf, idxbuf, d_h, d_w, out_match, out_midx, bb0, cnt, n);
    }
}